// Round 9
// baseline (167.302 us; speedup 1.0000x reference)
//
#include <hip/hip_runtime.h>
#include <math.h>

#define HH 2048
#define WW 2048
#define PLANE 4194304        // HH*WW
#define PITCH 45             // odd pitch, coprime with 32: conflict-free b32
#define PP (26*PITCH)        // 1170 floats per plane

// ws layout (bytes):
// 0     : float gwin[11]
// 64    : float gwin3[11]
// 128   : double lG[4]
// 256   : double lYpart[4*528]   (16896 B)
// 17408 : double qpart[8192]     (65536 B)

__device__ inline double wave_red(double v) {
#pragma unroll
  for (int o = 32; o > 0; o >>= 1) v += __shfl_down(v, o, 64);
  return v;
}

__global__ void k0_window(float* gwin, float* gwin3) {
  if (threadIdx.x == 0) {
    double e[11], s = 0.0;
    double sig = 11.0 / 6.0;
    for (int i = 0; i < 11; ++i) {
      double x = (double)(i - 5);
      e[i] = exp(-(x * x) / (2.0 * sig * sig));
      s += e[i];
    }
    for (int i = 0; i < 11; ++i) {
      gwin[i]  = (float)(e[i] / s);
      gwin3[i] = (float)(e[i] / (3.0 * s));
    }
  }
}

// k1: lY partial sums (unchanged; ~18 us).
__global__ __launch_bounds__(256) void k1_lY(const float* __restrict__ Ys,
                                             const float* __restrict__ gwin,
                                             double* __restrict__ lYpart) {
  int bid = blockIdx.x;
  int tid = threadIdx.x;
  double acc = 0.0;
  __shared__ float P[12];
  __shared__ double red[4];

  if (bid < 2048) {
    const float4* __restrict__ p = (const float4*)Ys;
    int base = bid * 6144 + tid;
#pragma unroll 1
    for (int gblk = 0; gblk < 3; ++gblk) {
      float ax = 0.f, ay = 0.f;
#pragma unroll
      for (int u = 0; u < 8; ++u) {
        float4 v = p[base + (gblk * 8 + u) * 256];
        ax += v.x + v.z;
        ay += v.y + v.w;
      }
      acc += (double)(ax + ay);
    }
  } else {
    int b = bid - 2048;             // 0..63
    int k = b >> 4, sub = b & 15;
    if (tid == 0) {
      float s = 0.f;
      for (int i = 0; i < 12; ++i) { P[i] = s; if (i < 11) s += gwin[i]; }
    }
    __syncthreads();
    const float4* __restrict__ Yk4 = (const float4*)(Ys + (size_t)k * 3 * PLANE);
    auto covP = [&](int r) -> float {
      if (r >= 5 && r <= 2042) return 1.0f;
      int dhi = r + 5; if (dhi > 10) dhi = 10;
      int dlo = r - 2042; if (dlo < 0) dlo = 0;
      return P[dhi + 1] - P[dlo];
    };
#pragma unroll 1
    for (int t = sub * 256 + tid; t < 39816; t += 4096) {
      int ch, row, g4;
      if (t < 15360) {
        ch = t / 5120;
        int r = (t % 5120) / 512;
        g4 = t & 511;
        row = (r < 5) ? r : r + 2038;
      } else {
        int u = t - 15360;
        ch = u / 8152;
        int rem = u % 8152;
        row = 5 + (rem >> 2);
        int gi = rem & 3;
        g4 = (gi < 2) ? gi : 508 + gi;
      }
      float4 v = Yk4[ch * 1048576 + row * 512 + g4];
      float cy = covP(row);
      int x0 = g4 << 2;
      float w0 = cy * covP(x0)     - 1.0f;
      float w1 = cy * covP(x0 + 1) - 1.0f;
      float w2 = cy * covP(x0 + 2) - 1.0f;
      float w3 = cy * covP(x0 + 3) - 1.0f;
      acc += (double)(w0 * v.x + w1 * v.y + w2 * v.z + w3 * v.w);
    }
  }

  acc = wave_red(acc);
  int lane = tid & 63, wid = tid >> 6;
  __syncthreads();
  if (lane == 0) red[wid] = acc;
  __syncthreads();
  if (tid == 0) {
    double tot = red[0] + red[1] + red[2] + red[3];
    if (bid < 2048) {
      int k = bid >> 9;
      lYpart[k * 528 + (bid & 511)] = tot;
    } else {
      int b = bid - 2048;
      lYpart[(b >> 4) * 528 + 512 + (b & 15)] = tot;
    }
  }
}

__global__ __launch_bounds__(256) void k2a_lG(const double* __restrict__ lYpart,
                                              double* __restrict__ lG) {
  __shared__ double red[4];
  for (int k = 0; k < 4; ++k) {
    const double* p = lYpart + k * 528;
    double v = p[threadIdx.x] + p[256 + threadIdx.x];
    if (threadIdx.x < 16) v += p[512 + threadIdx.x];
    v = wave_red(v);
    int lane = threadIdx.x & 63, wid = threadIdx.x >> 6;
    if (lane == 0) red[wid] = v;
    __syncthreads();
    if (threadIdx.x == 0) {
      double tot = red[0] + red[1] + red[2] + red[3];
      double lY = tot * (1.0 / 12582912.0);
      double d = lY - 0.5;
      lG[k] = exp(-(d * d) / 0.08);
    }
    __syncthreads();
  }
}

// k2 v9: 32x16 output tile, halo cols [x0-6, x0+37] (44 wide), rows
// [y0-5, y0+20] (26). Pitch 45 (conflict-free b32). float2 global loads.
// Row-owned H-blur (no internal barriers), column-owned V-blur.
// LDS = 14*26*45*4 = 65520 B; wave partials reuse prod after final barrier.
__global__ __launch_bounds__(512, 2) void k2_main(const float* __restrict__ X,
                                                  const float* __restrict__ Ys,
                                                  const float* __restrict__ gwin,
                                                  const float* __restrict__ gwin3,
                                                  const double* __restrict__ lG,
                                                  double* __restrict__ qpart) {
  __shared__ float prod[14 * PP];   // 65,520 B
  int bid = blockIdx.x;
  // XCD-compact swizzle (8192 % 8 == 0, bijective)
  int wg = (bid & 7) * 1024 + (bid >> 3);
  int tX = wg & 63, tY = wg >> 6;     // 64 x-tiles, 128 y-tiles
  int x0 = tX * 32, y0 = tY * 16;
  int tid = threadIdx.x;

  float g[11], g3[11];
#pragma unroll
  for (int i = 0; i < 11; ++i) { g[i] = gwin[i]; g3[i] = gwin3[i]; }

  // ---- Stage A: 26 rows x 11 float4-groups = 286 tasks, float2 loads ----
  if (tid < 286) {
    int row = tid / 11, gq = tid - row * 11;
    int gy = y0 - 5 + row;
    int gx = x0 - 6 + 4 * gq;          // even
    bool rok = (unsigned)gy < (unsigned)HH;
    size_t rb = (size_t)gy * WW;
    float v[15][4];
#pragma unroll
    for (int p = 0; p < 15; ++p) {
      const float* src = (p < 3) ? (X + (size_t)p * PLANE)
                                 : (Ys + (size_t)(p - 3) * PLANE);
#pragma unroll
      for (int h = 0; h < 2; ++h) {
        int xx = gx + 2 * h;
        float2 t = make_float2(0.f, 0.f);
        if (rok && (unsigned)xx < (unsigned)WW)
          t = *(const float2*)(src + rb + xx);
        v[p][2 * h]     = t.x;
        v[p][2 * h + 1] = t.y;
      }
    }
    int ob = row * PITCH + 4 * gq;
#pragma unroll
    for (int e = 0; e < 4; ++e) {
      float xa = v[0][e], xb = v[1][e], xc = v[2][e];
      prod[0 * PP + ob + e] = xa + xb + xc;
      prod[1 * PP + ob + e] = xa * xa + xb * xb + xc * xc;
#pragma unroll
      for (int k = 0; k < 4; ++k) {
        float ya = v[3 + 3 * k][e], yb = v[4 + 3 * k][e], yc = v[5 + 3 * k][e];
        prod[(2 + k) * PP + ob + e]  = ya + yb + yc;
        prod[(6 + k) * PP + ob + e]  = ya * ya + yb * yb + yc * yc;
        prod[(10 + k) * PP + ob + e] = xa * ya + xb * yb + xc * yc;
      }
    }
  }
  __syncthreads();

  // ---- Stage B: H-blur, row-owned register window (no internal barrier) ----
  // 14 fields x 26 rows = 364 tasks. Output col c (0..31) = blur center at
  // halo col c+6, window halo cols c+1 .. c+11.
  if (tid < 364) {
    int f = tid / 26, row = tid - f * 26;
    float* rp = prod + f * PP + row * PITCH;
    float w[44];
#pragma unroll
    for (int j = 0; j < 44; ++j) w[j] = rp[j];
#pragma unroll
    for (int c = 0; c < 32; ++c) {
      float s = 0.f;
#pragma unroll
      for (int d = 0; d < 11; ++d) s += g[d] * w[c + 1 + d];
      rp[c] = s;
    }
  }
  __syncthreads();

  // ---- Stage C: V-blur, column-owned (taps include /3) ----
  if (tid < 448) {                 // 14 fields x 32 columns
    int f = tid >> 5, tx = tid & 31;
    float* bp = prod + f * PP + tx;
    float col[26];
#pragma unroll
    for (int j = 0; j < 26; ++j) col[j] = bp[j * PITCH];
#pragma unroll
    for (int ty = 0; ty < 16; ++ty) {
      float s = 0.f;
#pragma unroll
      for (int d = 0; d < 11; ++d) s += g3[d] * col[ty + d];
      bp[ty * PITCH] = s;
    }
  }
  __syncthreads();

  // ---- Stage D: per-pixel fusion + block reduction ----
  {
    int dty = tid >> 5, dtx = tid & 31;   // full 16x32 tile
    int o = dty * PITCH + dtx;
    float b[14];
#pragma unroll
    for (int f = 0; f < 14; ++f) b[f] = prod[f * PP + o];
    float muX = b[0];
    float muX2 = muX * muX;
    float sigX = b[1] - muX2;
    float num = 0.f, den = 0.f;
    float best_sig = -1e30f, best_cs = 0.f;
#pragma unroll
    for (int k = 0; k < 4; ++k) {
      float muY  = b[2 + k];
      float sigY = b[6 + k] - muY * muY;
      float sXY  = b[10 + k] - muX * muY;
      float cs = (2.f * sXY + 9e-4f) / (sigX + sigY + 9e-4f);
      if (sigY > best_sig) { best_sig = sigY; best_cs = cs; }
      float dm = muY - 0.5f;
      float lL = expf(-dm * dm * 12.5f);
      float LY = (float)lG[k] * lL;
      num += LY * muY;
      den += LY;
    }
    float muYw = num / den;
    float l = (2.f * muX * muYw + 1e-4f) / (muX2 + muYw * muYw + 1e-4f);
    double v = (double)(l * best_cs);
    v = wave_red(v);
    int lane = tid & 63, wid = tid >> 6;
    __syncthreads();                       // all prod reads complete
    if (lane == 0) ((double*)prod)[wid] = v;   // reuse dead LDS for partials
    __syncthreads();
    if (tid == 0) {
      double t = 0.0;
      const double* qr = (const double*)prod;
#pragma unroll
      for (int i = 0; i < 8; ++i) t += qr[i];
      qpart[bid] = t;
    }
  }
}

__global__ __launch_bounds__(512) void k3_final(const double* __restrict__ qpart,
                                                float* __restrict__ out) {
  double acc = 0.0;
  for (int i = threadIdx.x; i < 8192; i += 512) acc += qpart[i];
  acc = wave_red(acc);
  __shared__ double red[8];
  int lane = threadIdx.x & 63, wid = threadIdx.x >> 6;
  if (lane == 0) red[wid] = acc;
  __syncthreads();
  if (threadIdx.x == 0)
    out[0] = (float)((red[0] + red[1] + red[2] + red[3] +
                      red[4] + red[5] + red[6] + red[7]) * (1.0 / 4194304.0));
}

extern "C" void kernel_launch(void* const* d_in, const int* in_sizes, int n_in,
                              void* d_out, int out_size, void* d_ws, size_t ws_size,
                              hipStream_t stream) {
  const float* X  = (const float*)d_in[0];
  const float* Ys = (const float*)d_in[1];
  char* ws = (char*)d_ws;
  float*  gwin   = (float*)(ws + 0);
  float*  gwin3  = (float*)(ws + 64);
  double* lG     = (double*)(ws + 128);
  double* lYpart = (double*)(ws + 256);
  double* qpart  = (double*)(ws + 17408);
  float* out = (float*)d_out;

  hipLaunchKernelGGL(k0_window, dim3(1), dim3(64), 0, stream, gwin, gwin3);
  hipLaunchKernelGGL(k1_lY, dim3(2112), dim3(256), 0, stream, Ys, gwin, lYpart);
  hipLaunchKernelGGL(k2a_lG, dim3(1), dim3(256), 0, stream, lYpart, lG);
  hipLaunchKernelGGL(k2_main, dim3(8192), dim3(512), 0, stream, X, Ys, gwin, gwin3, lG, qpart);
  hipLaunchKernelGGL(k3_final, dim3(1), dim3(512), 0, stream, qpart, out);
}